// Round 13
// baseline (57.974 us; speedup 1.0000x reference)
//
#include <hip/hip_runtime.h>
#include <hip/hip_bf16.h>

#define B_ 32
#define L_ 512
#define H_ 1024
#define E_ 8
#define R_ 16

typedef float f32x4 __attribute__((ext_vector_type(4)));
typedef __bf16 bf16x8 __attribute__((ext_vector_type(8)));
typedef __bf16 bf16x4 __attribute__((ext_vector_type(4)));

static __device__ __forceinline__ __bf16 f2b(float f) { return (__bf16)f; }

static __device__ __forceinline__ f32x4 MFMA(bf16x8 a, bf16x8 b, f32x4 c) {
  return __builtin_amdgcn_mfma_f32_16x16x32_bf16(a, b, c, 0, 0, 0);
}

// ---------------- prep: f32 weights -> bf16 in ws; + gates -----------------
__global__ __launch_bounds__(256) void moe_prep_kernel(
    const float* __restrict__ x, const float* __restrict__ rw,
    const float* __restrict__ ldown, const float* __restrict__ lup,
    __bf16* __restrict__ ldb, __bf16* __restrict__ lub,
    float* __restrict__ gws)
{
  const int bid = blockIdx.x;
  if (bid < 256) {                          // weight conversion: 2x131072 f32
    const int base = bid * 1024 + threadIdx.x * 4;
    const float* src; __bf16* dst; int off;
    if (base < 131072) { src = ldown; dst = ldb; off = base; }
    else               { src = lup;   dst = lub; off = base - 131072; }
    float4 v = *(const float4*)(src + off);
    bf16x4 bv = { f2b(v.x), f2b(v.y), f2b(v.z), f2b(v.w) };
    *(bf16x4*)(dst + off) = bv;
    return;
  }
  // gates for b = bid - 256
  const int b = bid - 256;
  const int t = threadIdx.x;
  const int e = t >> 5, s = t & 31;
  const float* cls = x + (size_t)b * L_ * H_;
  const float* w   = rw + (size_t)e * H_;
  float p = 0.f;
#pragma unroll
  for (int c = s; c < 256; c += 32) {
    float4 xv = *(const float4*)(cls + 4 * c);
    float4 wv = *(const float4*)(w + 4 * c);
    p += xv.x * wv.x + xv.y * wv.y + xv.z * wv.z + xv.w * wv.w;
  }
#pragma unroll
  for (int off = 16; off; off >>= 1) p += __shfl_down(p, off, 32);
  __shared__ float logits[E_];
  if (s == 0) logits[e] = p;
  __syncthreads();
  if (t == 0) {
    float m0 = -1e30f; int i0 = 0;
    for (int j = 0; j < E_; ++j) if (logits[j] > m0) { m0 = logits[j]; i0 = j; }
    float m1 = -1e30f; int i1 = 0;
    for (int j = 0; j < E_; ++j) if (j != i0 && logits[j] > m1) { m1 = logits[j]; i1 = j; }
    float eb = expf(m1 - m0), inv = 1.f / (1.f + eb);
    gws[b * 4 + 0] = inv;
    gws[b * 4 + 1] = eb * inv;
    ((int*)gws)[b * 4 + 2] = i0;
    ((int*)gws)[b * 4 + 3] = i1;
  }
}

// ---------------- gates-only fallback (no-ws path) -------------------------
__global__ __launch_bounds__(256) void moe_gates_kernel(
    const float* __restrict__ x, const float* __restrict__ rw,
    float* __restrict__ gws)
{
  const int b = blockIdx.x;
  const int t = threadIdx.x;
  const int e = t >> 5, s = t & 31;
  const float* cls = x + (size_t)b * L_ * H_;
  const float* w   = rw + (size_t)e * H_;
  float p = 0.f;
#pragma unroll
  for (int c = s; c < 256; c += 32) {
    float4 xv = *(const float4*)(cls + 4 * c);
    float4 wv = *(const float4*)(w + 4 * c);
    p += xv.x * wv.x + xv.y * wv.y + xv.z * wv.z + xv.w * wv.w;
  }
#pragma unroll
  for (int off = 16; off; off >>= 1) p += __shfl_down(p, off, 32);
  __shared__ float logits[E_];
  if (s == 0) logits[e] = p;
  __syncthreads();
  if (t == 0) {
    float m0 = -1e30f; int i0 = 0;
    for (int j = 0; j < E_; ++j) if (logits[j] > m0) { m0 = logits[j]; i0 = j; }
    float m1 = -1e30f; int i1 = 0;
    for (int j = 0; j < E_; ++j) if (j != i0 && logits[j] > m1) { m1 = logits[j]; i1 = j; }
    float eb = expf(m1 - m0), inv = 1.f / (1.f + eb);
    gws[b * 4 + 0] = inv;
    gws[b * 4 + 1] = eb * inv;
    ((int*)gws)[b * 4 + 2] = i0;
    ((int*)gws)[b * 4 + 3] = i1;
  }
}

// ---------------- main (bf16 weights): depth-2 pipelined, 2 barriers -------
// Structure identical to R12 (proven numerics); adds explicit rotating
// depth-2 software pipelines in phases A and B plus cross-barrier prefetch
// of phase-B's first iteration, to keep >=2 loads in flight per wave at all
// times (duty-cycle fix for the latency-serialization seen at VGPR=32).
__global__ __launch_bounds__(512, 8) void moe_main_kernel(
    const float* __restrict__ x,
    const __bf16* __restrict__ ldb, const __bf16* __restrict__ lub,
    const float* __restrict__ gws, float* __restrict__ out)
{
  __shared__ f32x4  red[8][2][64];          // 16,384 B
  __shared__ __bf16 dg[16][40];             //  1,280 B

  const int t    = threadIdx.x;
  const int w    = t >> 6;                  // 0..7
  const int lane = t & 63;
  const int gq   = lane >> 4;
  const int r16  = lane & 15;

  const int bid  = blockIdx.x;
  const int tile = (bid & 7) * 128 + (bid >> 3);   // XCD swizzle (bijective)
  const int b    = tile >> 5;
  const int l0   = (tile & 31) * 16;

  const float g0 = gws[b * 4 + 0];
  const float g1 = gws[b * 4 + 1];
  const int   e0 = ((const int*)gws)[b * 4 + 2];
  const int   e1 = ((const int*)gws)[b * 4 + 3];

  const float* xr = x + ((size_t)b * L_ + l0 + r16) * H_;   // lane's x row

  const __bf16* w0p = ldb + ((size_t)e0 * R_ + r16) * H_;
  const __bf16* w1p = ldb + ((size_t)e1 * R_ + r16) * H_;

  // ---- Phase A: K slice [w*128,(w+1)*128), 4 steps, depth-2 pipeline ------
  const int kb = w * 128 + 4 * gq;

  float4 xlo_c = *(const float4*)(xr + kb);
  float4 xhi_c = *(const float4*)(xr + kb + 16);
  bf16x4 a0_c = *(const bf16x4*)(w0p + kb);
  bf16x4 a1_c = *(const bf16x4*)(w0p + kb + 16);
  bf16x4 b0_c = *(const bf16x4*)(w1p + kb);
  bf16x4 b1_c = *(const bf16x4*)(w1p + kb + 16);

  f32x4 acc0 = {0.f, 0.f, 0.f, 0.f};
  f32x4 acc1 = {0.f, 0.f, 0.f, 0.f};

#pragma unroll
  for (int s = 0; s < 4; ++s) {
    float4 xlo_n, xhi_n; bf16x4 a0_n, a1_n, b0_n, b1_n;
    if (s < 3) {                             // issue next-iter loads FIRST
      const int kn = kb + (s + 1) * 32;
      xlo_n = *(const float4*)(xr + kn);
      xhi_n = *(const float4*)(xr + kn + 16);
      a0_n = *(const bf16x4*)(w0p + kn);
      a1_n = *(const bf16x4*)(w0p + kn + 16);
      b0_n = *(const bf16x4*)(w1p + kn);
      b1_n = *(const bf16x4*)(w1p + kn + 16);
    }
    bf16x8 xq = { f2b(xlo_c.x), f2b(xlo_c.y), f2b(xlo_c.z), f2b(xlo_c.w),
                  f2b(xhi_c.x), f2b(xhi_c.y), f2b(xhi_c.z), f2b(xhi_c.w) };
    bf16x8 wf0 = { a0_c[0],a0_c[1],a0_c[2],a0_c[3],
                   a1_c[0],a1_c[1],a1_c[2],a1_c[3] };
    bf16x8 wf1 = { b0_c[0],b0_c[1],b0_c[2],b0_c[3],
                   b1_c[0],b1_c[1],b1_c[2],b1_c[3] };
    acc0 = MFMA(wf0, xq, acc0);
    acc1 = MFMA(wf1, xq, acc1);
    if (s < 3) {
      xlo_c = xlo_n; xhi_c = xhi_n;
      a0_c = a0_n; a1_c = a1_n; b0_c = b0_n; b1_c = b1_n;
    }
  }

  // ---- cross-barrier prefetch: phase-B nt=0 loads issued BEFORE barriers --
  const __bf16* u0b = lub + (size_t)e0 * H_ * R_;
  const __bf16* u1b = lub + (size_t)e1 * H_ * R_;
  const int h00 = w * 128;

  bf16x4 ulo_c = *(const bf16x4*)(u0b + (size_t)(h00 + r16) * R_ + 4 * gq);
  bf16x4 uhi_c = *(const bf16x4*)(u1b + (size_t)(h00 + r16) * R_ + 4 * gq);
  float4 rx_c  = *(const float4*)(xr + h00 + 4 * gq);

  red[w][0][lane] = acc0;
  red[w][1][lane] = acc1;
  __syncthreads();

  // ---- reduce 8 K-parts + gate + pack dg[l][p] (D^T frag layout) ----------
  if (t < 128) {
    const int tl = t >> 6, slot = t & 63;
    f32x4 v = red[0][tl][slot];
#pragma unroll
    for (int q = 1; q < 8; ++q) v += red[q][tl][slot];
    const float g = tl ? g1 : g0;
    const int l  = slot & 15;
    const int p0 = tl * 16 + (slot >> 4) * 4;
#pragma unroll
    for (int j = 0; j < 4; ++j) dg[l][p0 + j] = f2b(v[j] * g);
  }
  __syncthreads();

  // ---- Phase B: h slice [w*128,(w+1)*128), 8 steps, depth-2 pipeline ------
  bf16x8 dfrag;
#pragma unroll
  for (int j = 0; j < 4; ++j) {
    dfrag[j]     = dg[r16][4 * gq + j];         // k=4gq+j      (e0)
    dfrag[4 + j] = dg[r16][16 + 4 * gq + j];    // k=16+4gq+j   (e1)
  }

  float* outr = out + ((size_t)b * L_ + l0 + r16) * H_;

#pragma unroll
  for (int nt = 0; nt < 8; ++nt) {
    bf16x4 ulo_n, uhi_n; float4 rx_n;
    if (nt < 7) {                            // issue next-iter loads FIRST
      const int ha = h00 + (nt + 1) * 16 + r16;
      ulo_n = *(const bf16x4*)(u0b + (size_t)ha * R_ + 4 * gq);
      uhi_n = *(const bf16x4*)(u1b + (size_t)ha * R_ + 4 * gq);
      rx_n  = *(const float4*)(xr + h00 + (nt + 1) * 16 + 4 * gq);
    }
    bf16x8 uf = { ulo_c[0],ulo_c[1],ulo_c[2],ulo_c[3],
                  uhi_c[0],uhi_c[1],uhi_c[2],uhi_c[3] };
    f32x4 acc = { rx_c.x, rx_c.y, rx_c.z, rx_c.w };
    acc = MFMA(uf, dfrag, acc);
    *(float4*)(outr + h00 + nt * 16 + 4 * gq) = *(float4*)&acc;
    if (nt < 7) { ulo_c = ulo_n; uhi_c = uhi_n; rx_c = rx_n; }
  }
}

// ---------------- f32-weight fallback (only if ws too small) ---------------
__global__ __launch_bounds__(512, 8) void moe_main_f32_kernel(
    const float* __restrict__ x,
    const float* __restrict__ ldf, const float* __restrict__ luf,
    const float* __restrict__ gws, float* __restrict__ out)
{
  __shared__ f32x4  red[8][2][64];
  __shared__ __bf16 dg[16][40];

  const int t    = threadIdx.x;
  const int w    = t >> 6;
  const int lane = t & 63;
  const int gq   = lane >> 4;
  const int r16  = lane & 15;

  const int bid  = blockIdx.x;
  const int tile = (bid & 7) * 128 + (bid >> 3);
  const int b    = tile >> 5;
  const int l0   = (tile & 31) * 16;

  const float g0 = gws[b * 4 + 0];
  const float g1 = gws[b * 4 + 1];
  const int   e0 = ((const int*)gws)[b * 4 + 2];
  const int   e1 = ((const int*)gws)[b * 4 + 3];

  const float* xr = x + ((size_t)b * L_ + l0 + r16) * H_;

  f32x4 acc0 = {0.f, 0.f, 0.f, 0.f};
  f32x4 acc1 = {0.f, 0.f, 0.f, 0.f};
#pragma unroll
  for (int s = 0; s < 4; ++s) {
    const int kl = w * 128 + s * 32 + 4 * gq;
    float4 xlo = *(const float4*)(xr + kl);
    float4 xhi = *(const float4*)(xr + kl + 16);
    bf16x8 xq = { f2b(xlo.x), f2b(xlo.y), f2b(xlo.z), f2b(xlo.w),
                  f2b(xhi.x), f2b(xhi.y), f2b(xhi.z), f2b(xhi.w) };
    const float* w0p = ldf + ((size_t)e0 * R_ + r16) * H_;
    const float* w1p = ldf + ((size_t)e1 * R_ + r16) * H_;
    float4 alo = *(const float4*)(w0p + kl);
    float4 ahi = *(const float4*)(w0p + kl + 16);
    float4 blo = *(const float4*)(w1p + kl);
    float4 bhi = *(const float4*)(w1p + kl + 16);
    bf16x8 wf0 = { f2b(alo.x), f2b(alo.y), f2b(alo.z), f2b(alo.w),
                   f2b(ahi.x), f2b(ahi.y), f2b(ahi.z), f2b(ahi.w) };
    bf16x8 wf1 = { f2b(blo.x), f2b(blo.y), f2b(blo.z), f2b(blo.w),
                   f2b(bhi.x), f2b(bhi.y), f2b(bhi.z), f2b(bhi.w) };
    acc0 = MFMA(wf0, xq, acc0);
    acc1 = MFMA(wf1, xq, acc1);
  }
  red[w][0][lane] = acc0;
  red[w][1][lane] = acc1;
  __syncthreads();

  if (t < 128) {
    const int tl = t >> 6, slot = t & 63;
    f32x4 v = red[0][tl][slot];
#pragma unroll
    for (int q = 1; q < 8; ++q) v += red[q][tl][slot];
    const float g = tl ? g1 : g0;
    const int l  = slot & 15;
    const int p0 = tl * 16 + (slot >> 4) * 4;
#pragma unroll
    for (int j = 0; j < 4; ++j) dg[l][p0 + j] = f2b(v[j] * g);
  }
  __syncthreads();

  bf16x8 dfrag;
#pragma unroll
  for (int j = 0; j < 4; ++j) {
    dfrag[j]     = dg[r16][4 * gq + j];
    dfrag[4 + j] = dg[r16][16 + 4 * gq + j];
  }

  float* outr = out + ((size_t)b * L_ + l0 + r16) * H_;
#pragma unroll
  for (int nt = 0; nt < 8; ++nt) {
    const int h0 = w * 128 + nt * 16;
    const int ha = h0 + r16;
    float4 ulo = *(const float4*)(luf + ((size_t)e0 * H_ + ha) * R_ + 4 * gq);
    float4 uhi = *(const float4*)(luf + ((size_t)e1 * H_ + ha) * R_ + 4 * gq);
    bf16x8 uf = { f2b(ulo.x), f2b(ulo.y), f2b(ulo.z), f2b(ulo.w),
                  f2b(uhi.x), f2b(uhi.y), f2b(uhi.z), f2b(uhi.w) };
    float4 rx = *(const float4*)(xr + h0 + 4 * gq);
    f32x4 acc = { rx.x, rx.y, rx.z, rx.w };
    acc = MFMA(uf, dfrag, acc);
    *(float4*)(outr + h0 + 4 * gq) = *(float4*)&acc;
  }
}

extern "C" void kernel_launch(void* const* d_in, const int* in_sizes, int n_in,
                              void* d_out, int out_size, void* d_ws, size_t ws_size,
                              hipStream_t stream) {
  const float* x  = (const float*)d_in[0];
  const float* rw = (const float*)d_in[1];
  const float* ld = (const float*)d_in[2];
  const float* lu = (const float*)d_in[3];
  float* outp = (float*)d_out;

  float*  gws = (float*)d_ws;                         // 512 B
  __bf16* ldb = (__bf16*)((char*)d_ws + 1024);        // 256 KB
  __bf16* lub = ldb + 131072;                         // 256 KB

  if (ws_size >= 1024 + 2 * 131072 * sizeof(__bf16)) {
    hipLaunchKernelGGL(moe_prep_kernel, dim3(256 + B_), dim3(256), 0, stream,
                       x, rw, ld, lu, ldb, lub, gws);
    hipLaunchKernelGGL(moe_main_kernel, dim3(1024), dim3(512), 0, stream,
                       x, ldb, lub, gws, outp);
  } else {
    hipLaunchKernelGGL(moe_gates_kernel, dim3(B_), dim3(256), 0, stream,
                       x, rw, gws);
    hipLaunchKernelGGL(moe_main_f32_kernel, dim3(1024), dim3(512), 0, stream,
                       x, ld, lu, gws, outp);
  }
}

// Round 14
// 43.102 us; speedup vs baseline: 1.3450x; 1.3450x over previous
//
#include <hip/hip_runtime.h>
#include <hip/hip_bf16.h>

#define B_ 32
#define L_ 512
#define H_ 1024
#define E_ 8
#define R_ 16

typedef float f32x4 __attribute__((ext_vector_type(4)));
typedef __bf16 bf16x8 __attribute__((ext_vector_type(8)));
typedef __bf16 bf16x4 __attribute__((ext_vector_type(4)));

static __device__ __forceinline__ __bf16 f2b(float f) { return (__bf16)f; }

static __device__ __forceinline__ f32x4 MFMA(bf16x8 a, bf16x8 b, f32x4 c) {
  return __builtin_amdgcn_mfma_f32_16x16x32_bf16(a, b, c, 0, 0, 0);
}

// ---------------- prep: f32 weights -> bf16 in ws; + gates -----------------
__global__ __launch_bounds__(256) void moe_prep_kernel(
    const float* __restrict__ x, const float* __restrict__ rw,
    const float* __restrict__ ldown, const float* __restrict__ lup,
    __bf16* __restrict__ ldb, __bf16* __restrict__ lub,
    float* __restrict__ gws)
{
  const int bid = blockIdx.x;
  if (bid < 256) {                          // weight conversion: 2x131072 f32
    const int base = bid * 1024 + threadIdx.x * 4;
    const float* src; __bf16* dst; int off;
    if (base < 131072) { src = ldown; dst = ldb; off = base; }
    else               { src = lup;   dst = lub; off = base - 131072; }
    float4 v = *(const float4*)(src + off);
    bf16x4 bv = { f2b(v.x), f2b(v.y), f2b(v.z), f2b(v.w) };
    *(bf16x4*)(dst + off) = bv;
    return;
  }
  // gates for b = bid - 256
  const int b = bid - 256;
  const int t = threadIdx.x;
  const int e = t >> 5, s = t & 31;
  const float* cls = x + (size_t)b * L_ * H_;
  const float* w   = rw + (size_t)e * H_;
  float p = 0.f;
#pragma unroll
  for (int c = s; c < 256; c += 32) {
    float4 xv = *(const float4*)(cls + 4 * c);
    float4 wv = *(const float4*)(w + 4 * c);
    p += xv.x * wv.x + xv.y * wv.y + xv.z * wv.z + xv.w * wv.w;
  }
#pragma unroll
  for (int off = 16; off; off >>= 1) p += __shfl_down(p, off, 32);
  __shared__ float logits[E_];
  if (s == 0) logits[e] = p;
  __syncthreads();
  if (t == 0) {
    float m0 = -1e30f; int i0 = 0;
    for (int j = 0; j < E_; ++j) if (logits[j] > m0) { m0 = logits[j]; i0 = j; }
    float m1 = -1e30f; int i1 = 0;
    for (int j = 0; j < E_; ++j) if (j != i0 && logits[j] > m1) { m1 = logits[j]; i1 = j; }
    float eb = expf(m1 - m0), inv = 1.f / (1.f + eb);
    gws[b * 4 + 0] = inv;
    gws[b * 4 + 1] = eb * inv;
    ((int*)gws)[b * 4 + 2] = i0;
    ((int*)gws)[b * 4 + 3] = i1;
  }
}

// ---------------- gates-only fallback (no-ws path) -------------------------
__global__ __launch_bounds__(256) void moe_gates_kernel(
    const float* __restrict__ x, const float* __restrict__ rw,
    float* __restrict__ gws)
{
  const int b = blockIdx.x;
  const int t = threadIdx.x;
  const int e = t >> 5, s = t & 31;
  const float* cls = x + (size_t)b * L_ * H_;
  const float* w   = rw + (size_t)e * H_;
  float p = 0.f;
#pragma unroll
  for (int c = s; c < 256; c += 32) {
    float4 xv = *(const float4*)(cls + 4 * c);
    float4 wv = *(const float4*)(w + 4 * c);
    p += xv.x * wv.x + xv.y * wv.y + xv.z * wv.z + xv.w * wv.w;
  }
#pragma unroll
  for (int off = 16; off; off >>= 1) p += __shfl_down(p, off, 32);
  __shared__ float logits[E_];
  if (s == 0) logits[e] = p;
  __syncthreads();
  if (t == 0) {
    float m0 = -1e30f; int i0 = 0;
    for (int j = 0; j < E_; ++j) if (logits[j] > m0) { m0 = logits[j]; i0 = j; }
    float m1 = -1e30f; int i1 = 0;
    for (int j = 0; j < E_; ++j) if (j != i0 && logits[j] > m1) { m1 = logits[j]; i1 = j; }
    float eb = expf(m1 - m0), inv = 1.f / (1.f + eb);
    gws[b * 4 + 0] = inv;
    gws[b * 4 + 1] = eb * inv;
    ((int*)gws)[b * 4 + 2] = i0;
    ((int*)gws)[b * 4 + 3] = i1;
  }
}

// ---------------- main: R10 structure + in-place bf16 results + streaming
// epilogue. Phase B's MFMA output overwrites (in LDS, bf16) the exact quad
// that supplied its residual C-init; a final phase streams whole rows to
// global with 512B-contiguous stores per instruction (probe pattern).
// Row stride 1036 elems = 518 dw (6 mod 32) -> 16 rows on distinct banks.
template<int BW>
__global__ __launch_bounds__(512, 4) void moe_main_kernel(
    const float* __restrict__ x,
    const __bf16* __restrict__ ldb, const __bf16* __restrict__ lub,
    const float* __restrict__ ldf, const float* __restrict__ luf,
    const float* __restrict__ gws, float* __restrict__ out)
{
  constexpr int XW = 1036;                  // 518 dwords/row, %32 == 6
  __shared__ __bf16 xs[16][XW];             // 33,152 B: x in, OUT (bf16) after B
  __shared__ f32x4  red[8][2][64];          // 16,384 B
  __shared__ __bf16 dg[16][40];             //  1,280 B

  const int t    = threadIdx.x;
  const int w    = t >> 6;                  // 0..7
  const int lane = t & 63;
  const int gq   = lane >> 4;
  const int r16  = lane & 15;

  const int bid  = blockIdx.x;
  const int tile = (bid & 7) * 128 + (bid >> 3);   // XCD swizzle (bijective)
  const int b    = tile >> 5;
  const int l0   = (tile & 31) * 16;

  const float g0 = gws[b * 4 + 0];
  const float g1 = gws[b * 4 + 1];
  const int   e0 = ((const int*)gws)[b * 4 + 2];
  const int   e1 = ((const int*)gws)[b * 4 + 3];

  const float* xb = x + ((size_t)b * L_ + l0) * H_;

  // ---- stage X tile as bf16 (wave w: rows 2w,2w+1; row-contiguous reads) --
  {
    const int row = 2 * w + (lane >> 5);
    const int c0  = (lane & 31) * 4;
    const float* xrr = xb + (size_t)row * H_;
#pragma unroll
    for (int i = 0; i < 8; ++i) {
      float4 v = *(const float4*)(xrr + c0 + i * 128);
      bf16x4 bv = { f2b(v.x), f2b(v.y), f2b(v.z), f2b(v.w) };
      *(bf16x4*)&xs[row][c0 + i * 128] = bv;
    }
  }
  __syncthreads();

  // ---- Phase A: wave w handles K slice [w*128, (w+1)*128) -----------------
  f32x4 acc0 = {0.f, 0.f, 0.f, 0.f};
  f32x4 acc1 = {0.f, 0.f, 0.f, 0.f};
#pragma unroll
  for (int s = 0; s < 4; ++s) {
    const int kl = w * 128 + s * 32 + 4 * gq;
    bf16x4 xlo = *(const bf16x4*)&xs[r16][kl];
    bf16x4 xhi = *(const bf16x4*)&xs[r16][kl + 16];
    bf16x8 xq = { xlo[0], xlo[1], xlo[2], xlo[3],
                  xhi[0], xhi[1], xhi[2], xhi[3] };
    bf16x8 wf0, wf1;
    if constexpr (BW) {
      const __bf16* w0p = ldb + ((size_t)e0 * R_ + r16) * H_;
      const __bf16* w1p = ldb + ((size_t)e1 * R_ + r16) * H_;
      bf16x4 a0 = *(const bf16x4*)(w0p + kl);
      bf16x4 a1 = *(const bf16x4*)(w0p + kl + 16);
      bf16x4 b0 = *(const bf16x4*)(w1p + kl);
      bf16x4 b1 = *(const bf16x4*)(w1p + kl + 16);
      wf0 = bf16x8{ a0[0],a0[1],a0[2],a0[3], a1[0],a1[1],a1[2],a1[3] };
      wf1 = bf16x8{ b0[0],b0[1],b0[2],b0[3], b1[0],b1[1],b1[2],b1[3] };
    } else {
      const float* w0p = ldf + ((size_t)e0 * R_ + r16) * H_;
      const float* w1p = ldf + ((size_t)e1 * R_ + r16) * H_;
      float4 alo = *(const float4*)(w0p + kl);
      float4 ahi = *(const float4*)(w0p + kl + 16);
      float4 blo = *(const float4*)(w1p + kl);
      float4 bhi = *(const float4*)(w1p + kl + 16);
      wf0 = bf16x8{ f2b(alo.x), f2b(alo.y), f2b(alo.z), f2b(alo.w),
                    f2b(ahi.x), f2b(ahi.y), f2b(ahi.z), f2b(ahi.w) };
      wf1 = bf16x8{ f2b(blo.x), f2b(blo.y), f2b(blo.z), f2b(blo.w),
                    f2b(bhi.x), f2b(bhi.y), f2b(bhi.z), f2b(bhi.w) };
    }
    acc0 = MFMA(wf0, xq, acc0);
    acc1 = MFMA(wf1, xq, acc1);
  }
  red[w][0][lane] = acc0;
  red[w][1][lane] = acc1;
  __syncthreads();

  // ---- reduce 8 K-parts + gate + pack dg[l][p] (D^T frag layout) ----------
  if (t < 128) {
    const int tl = t >> 6, slot = t & 63;
    f32x4 v = red[0][tl][slot];
#pragma unroll
    for (int q = 1; q < 8; ++q) v += red[q][tl][slot];
    const float g = tl ? g1 : g0;
    const int l  = slot & 15;
    const int p0 = tl * 16 + (slot >> 4) * 4;
#pragma unroll
    for (int j = 0; j < 4; ++j) dg[l][p0 + j] = f2b(v[j] * g);
  }
  __syncthreads();

  // ---- Phase B: wave w covers h in [w*128, (w+1)*128); in-place results ---
  bf16x8 dfrag;
#pragma unroll
  for (int j = 0; j < 4; ++j) {
    dfrag[j]     = dg[r16][4 * gq + j];         // k=4gq+j      (e0)
    dfrag[4 + j] = dg[r16][16 + 4 * gq + j];    // k=16+4gq+j   (e1)
  }

#pragma unroll
  for (int nt = 0; nt < 8; ++nt) {
    const int h0 = w * 128 + nt * 16;
    const int ha = h0 + r16;
    bf16x8 uf;
    if constexpr (BW) {
      bf16x4 ulo = *(const bf16x4*)(lub + ((size_t)e0 * H_ + ha) * R_ + 4 * gq);
      bf16x4 uhi = *(const bf16x4*)(lub + ((size_t)e1 * H_ + ha) * R_ + 4 * gq);
      uf = bf16x8{ ulo[0],ulo[1],ulo[2],ulo[3], uhi[0],uhi[1],uhi[2],uhi[3] };
    } else {
      float4 ulo = *(const float4*)(luf + ((size_t)e0 * H_ + ha) * R_ + 4 * gq);
      float4 uhi = *(const float4*)(luf + ((size_t)e1 * H_ + ha) * R_ + 4 * gq);
      uf = bf16x8{ f2b(ulo.x), f2b(ulo.y), f2b(ulo.z), f2b(ulo.w),
                   f2b(uhi.x), f2b(uhi.y), f2b(uhi.z), f2b(uhi.w) };
    }
    bf16x4 rx = *(const bf16x4*)&xs[r16][h0 + 4 * gq];    // residual (bf16)
    f32x4 acc = { (float)rx[0], (float)rx[1], (float)rx[2], (float)rx[3] };
    acc = MFMA(uf, dfrag, acc);
    bf16x4 ov = { f2b(acc[0]), f2b(acc[1]), f2b(acc[2]), f2b(acc[3]) };
    *(bf16x4*)&xs[r16][h0 + 4 * gq] = ov;     // in-place: same lane, same quad
  }
  __syncthreads();

  // ---- epilogue: stream whole rows out (512B contiguous per instruction) --
  {
    const int row = 2 * w + (lane >> 5);
    const int l32 = lane & 31;
    float* outrow = out + ((size_t)b * L_ + l0 + row) * H_;
#pragma unroll
    for (int it = 0; it < 8; ++it) {
      const int col = it * 128 + l32 * 4;
      bf16x4 v = *(const bf16x4*)&xs[row][col];
      float4 o = { (float)v[0], (float)v[1], (float)v[2], (float)v[3] };
      *(float4*)(outrow + col) = o;
    }
  }
}

extern "C" void kernel_launch(void* const* d_in, const int* in_sizes, int n_in,
                              void* d_out, int out_size, void* d_ws, size_t ws_size,
                              hipStream_t stream) {
  const float* x  = (const float*)d_in[0];
  const float* rw = (const float*)d_in[1];
  const float* ld = (const float*)d_in[2];
  const float* lu = (const float*)d_in[3];
  float* outp = (float*)d_out;

  float*  gws = (float*)d_ws;                         // 512 B
  __bf16* ldb = (__bf16*)((char*)d_ws + 1024);        // 256 KB
  __bf16* lub = ldb + 131072;                         // 256 KB

  if (ws_size >= 1024 + 2 * 131072 * sizeof(__bf16)) {
    hipLaunchKernelGGL(moe_prep_kernel, dim3(256 + B_), dim3(256), 0, stream,
                       x, rw, ld, lu, ldb, lub, gws);
    hipLaunchKernelGGL(moe_main_kernel<1>, dim3(1024), dim3(512), 0, stream,
                       x, ldb, lub, nullptr, nullptr, gws, outp);
  } else {
    hipLaunchKernelGGL(moe_gates_kernel, dim3(B_), dim3(256), 0, stream,
                       x, rw, gws);
    hipLaunchKernelGGL(moe_main_kernel<0>, dim3(1024), dim3(512), 0, stream,
                       x, nullptr, nullptr, ld, lu, gws, outp);
  }
}